// Round 10
// baseline (53.117 us; speedup 1.0000x reference)
//
#include <hip/hip_runtime.h>
#include <hip/hip_bf16.h>
#include <math.h>
#include <stdint.h>

// SpectralPooling: x (4,32,64,64,64) f32 -> out (4,32,32,32,32) f32.
// Separable: out[bc,k,j,l] = sum_{d,h,w} A[k,d]A[j,h]A[l,w] x[bc,d,h,w],
// A = (32x64) fused DCT64->crop32->IDCT32 matrix.
// k_hw (MFMA bf16, R9-exact): per slab (bc,d): U = X·A^T ; O^T = Ut·A^T -> w1b bf16
// k_d  (R10): 2 p per thread, f32x2 accumulators -> v_pk_fma_f32 (halves VALU stream)
// build (R10): 64 blocks x 64 threads, 1 element/thread
//
// MFMA conventions (mfma_f32_16x16x32_bf16), HW-verified by R3-R9 passing:
//   A-op: lane m = lane&15, k = 8*(lane>>4)+jj ; B-op same map (k-perm cancels)
//   C/D : col = lane&15, row = 4*(lane>>4)+reg

#define PI_F 3.14159265358979323846f

typedef __attribute__((ext_vector_type(4))) float f32x4;
typedef __attribute__((ext_vector_type(2))) float f32x2;
typedef __attribute__((ext_vector_type(8))) short bf16x8;

union U16x8 { uint4 q; bf16x8 v; uint32_t w[4]; };

// pair f32 -> packed bf16 (RNE) ; compiles to v_cvt_pk_bf16_f32
__device__ __forceinline__ uint32_t pk(float a, float b) {
    union { __hip_bfloat162 h; uint32_t u; } c;
    c.h = __float22bfloat162_rn(make_float2(a, b));
    return c.u;
}

__device__ __forceinline__ unsigned short bf16r(float x) {
    union { float f; uint32_t u; } c; c.f = x;
    uint32_t r = (c.u + 0x7FFFu + ((c.u >> 16) & 1u)) >> 16;  // RNE (table build only)
    return (unsigned short)r;
}

__device__ __forceinline__ float Aelem(int i, int d) {
    const float s1 = sqrtf(1.0f / 32.0f), s2 = sqrtf(2.0f / 32.0f);
    const float t1 = sqrtf(1.0f / 64.0f), t2 = sqrtf(2.0f / 64.0f);
    float acc = 0.f;
    for (int k = 0; k < 32; ++k) {
        int n1 = ((2 * i + 1) * k) & 127;   // cos(pi*n1/64)
        int n2 = ((2 * d + 1) * k) & 255;   // cos(pi*n2/128)
        float c1 = cosf((float)n1 * (PI_F / 64.0f));
        float c2 = cosf((float)n2 * (PI_F / 128.0f));
        acc += ((k == 0) ? s1 : s2) * ((k == 0) ? t1 : t2) * c1 * c2;
    }
    return acc;
}

// ---- tables: At[64][32] f32 (k_d) + F frag table bf16 (k_hw). 64 x 64. ----
__global__ __launch_bounds__(64) void build_tables(float* __restrict__ At,
                                                   unsigned short* __restrict__ F) {
    int e = blockIdx.x * 64 + threadIdx.x;
    if (e < 2048) {
        int d = e >> 5, i = e & 31;
        At[e] = Aelem(i, d);
    } else if (e < 4096) {
        int f = e - 2048;
        int jj = f & 7, lane = (f >> 3) & 63, tk = f >> 9;
        int tt = tk >> 1, kt = tk & 1;
        int row = tt * 16 + (lane & 15);
        int col = kt * 32 + ((lane >> 4) << 3) + jj;
        F[f] = bf16r(Aelem(row, col));
    }
}

// ---- k_hw: R9-exact. 4 waves/block, one slab per wave, wave-private LDS. ----
__global__ __launch_bounds__(256, 4) void k_hw(const float* __restrict__ x,
                                               const unsigned short* __restrict__ F,
                                               unsigned short* __restrict__ w1b) {
    __shared__ unsigned short Ut[4][2048];   // per-wave Ut[l][h] bf16, XOR-swizzled

    const int t = threadIdx.x;
    const int wv = t >> 6, ln = t & 63;
    const int lm = ln & 15, lg = ln >> 4;
    const size_t slab = (size_t)blockIdx.x * 4 + wv;

    // constant B-operand frags
    bf16x8 Ff[2][2];
    {
        const uint4* fp = (const uint4*)F;
        #pragma unroll
        for (int tt = 0; tt < 2; ++tt)
            #pragma unroll
            for (int kt = 0; kt < 2; ++kt) {
                U16x8 u; u.q = fp[(tt * 2 + kt) * 64 + ln];
                Ff[tt][kt] = u.v;
            }
    }

    // ---- issue all 16 x-loads up front ----
    const float* xs = x + slab * 4096;
    uint4 raw[16];
    #pragma unroll
    for (int mt = 0; mt < 4; ++mt)
        #pragma unroll
        for (int kt = 0; kt < 2; ++kt) {
            const uint4* p = (const uint4*)(xs + (mt * 16 + lm) * 64 + kt * 32 + (lg << 3));
            raw[(mt * 2 + kt) * 2 + 0] = p[0];
            raw[(mt * 2 + kt) * 2 + 1] = p[1];
        }

    // ---- stage B: U[h][l] = sum_w X[h][w] * A[l][w] ----
    f32x4 accu[4][2];
    #pragma unroll
    for (int mt = 0; mt < 4; ++mt)
        #pragma unroll
        for (int nt = 0; nt < 2; ++nt)
            accu[mt][nt] = (f32x4){0.f, 0.f, 0.f, 0.f};

    #pragma unroll
    for (int mt = 0; mt < 4; ++mt) {
        #pragma unroll
        for (int kt = 0; kt < 2; ++kt) {
            const float* f0 = (const float*)&raw[(mt * 2 + kt) * 2];
            U16x8 xf;
            #pragma unroll
            for (int e = 0; e < 4; ++e)
                xf.w[e] = pk(f0[2 * e], f0[2 * e + 1]);   // v_cvt_pk_bf16_f32
            #pragma unroll
            for (int nt = 0; nt < 2; ++nt)
                accu[mt][nt] = __builtin_amdgcn_mfma_f32_16x16x32_bf16(
                    xf.v, Ff[nt][kt], accu[mt][nt], 0, 0, 0);
        }
    }

    // ---- transpose U -> Ut[l][h] (bf16, XOR-swizzled), wave-private ----
    unsigned short* ut = Ut[wv];
    #pragma unroll
    for (int mt = 0; mt < 4; ++mt)
        #pragma unroll
        for (int nt = 0; nt < 2; ++nt) {
            int lo = nt * 16 + lm;               // Ut row (= l)
            int h0 = mt * 16 + (lg << 2);        // 4 consecutive h
            uint32_t w0 = pk(accu[mt][nt][0], accu[mt][nt][1]);
            uint32_t w1v = pk(accu[mt][nt][2], accu[mt][nt][3]);
            uint32_t byte = (uint32_t)(lo * 128 + 2 * h0);
            byte ^= (uint32_t)((lo & 7) << 4);   // bank swizzle
            *(uint2*)((char*)ut + byte) = make_uint2(w0, w1v);
        }
    __builtin_amdgcn_wave_barrier();

    // ---- stage C: O^T[l][j] = sum_h Ut[l][h] * A[j][h] ----
    f32x4 acco[2][2];
    #pragma unroll
    for (int mt = 0; mt < 2; ++mt)
        #pragma unroll
        for (int nt = 0; nt < 2; ++nt)
            acco[mt][nt] = (f32x4){0.f, 0.f, 0.f, 0.f};

    #pragma unroll
    for (int mt = 0; mt < 2; ++mt) {
        #pragma unroll
        for (int kt = 0; kt < 2; ++kt) {
            int lo = mt * 16 + lm;
            uint32_t byte = (uint32_t)(lo * 128 + kt * 64 + (lg << 4));
            byte ^= (uint32_t)((lo & 7) << 4);
            bf16x8 uf = *(const bf16x8*)((const char*)ut + byte);  // ds_read_b128
            #pragma unroll
            for (int nt = 0; nt < 2; ++nt)
                acco[mt][nt] = __builtin_amdgcn_mfma_f32_16x16x32_bf16(
                    uf, Ff[nt][kt], acco[mt][nt], 0, 0, 0);
        }
    }

    // ---- direct packed store: lane owns 4 consecutive l per (mt,nt) ----
    #pragma unroll
    for (int mt = 0; mt < 2; ++mt)
        #pragma unroll
        for (int nt = 0; nt < 2; ++nt) {
            uint32_t u0 = pk(acco[mt][nt][0], acco[mt][nt][1]);
            uint32_t u1 = pk(acco[mt][nt][2], acco[mt][nt][3]);
            int j  = nt * 16 + lm;
            int l0 = mt * 16 + (lg << 2);
            *(uint2*)(w1b + slab * 1024 + j * 32 + l0) = make_uint2(u0, u1);
        }
}

// ---- k_d: packed-FMA version. grid = 128 bc x 2 kh x 2 pq = 512 blocks ----
// out[bc][kh*16+kk][p] = sum_d At[d][kh*16+kk] * w1b[bc][d][p], 2 p per thread,
// f32x2 accumulators -> v_pk_fma_f32 (halved VALU instruction stream).
__global__ __launch_bounds__(256, 4) void k_d(const unsigned short* __restrict__ w1b,
                                              const float* __restrict__ At,
                                              float* __restrict__ out) {
    const int t = threadIdx.x;
    const int bc = blockIdx.x >> 2;
    const int kh = (blockIdx.x >> 1) & 1;
    const int pq = blockIdx.x & 1;
    const int p0 = pq * 512 + t * 2;
    const unsigned short* src = w1b + (size_t)bc * 65536 + p0;
    f32x2 acc[16];
    #pragma unroll
    for (int k = 0; k < 16; ++k) acc[k] = (f32x2){0.f, 0.f};
    #pragma unroll 8
    for (int d = 0; d < 64; ++d) {
        uint32_t u = *(const uint32_t*)(src + d * 1024);      // 2 bf16 (p0, p0+1)
        f32x2 v;
        v.x = __uint_as_float(u << 16);
        v.y = __uint_as_float(u & 0xFFFF0000u);
        const float* arow = At + d * 32 + kh * 16;            // wave-uniform -> s_load
        #pragma unroll
        for (int k = 0; k < 16; ++k)
            acc[k] += arow[k] * v;                            // v_pk_fma_f32
    }
    float* dst = out + (size_t)bc * 32768 + (size_t)kh * 16384 + p0;
    #pragma unroll
    for (int k = 0; k < 16; ++k)
        *(float2*)(dst + k * 1024) = make_float2(acc[k].x, acc[k].y);
}

extern "C" void kernel_launch(void* const* d_in, const int* in_sizes, int n_in,
                              void* d_out, int out_size, void* d_ws, size_t ws_size,
                              hipStream_t stream) {
    const float* x = (const float*)d_in[0];
    float* out = (float*)d_out;

    float* At           = (float*)d_ws;                           // 8 KiB
    unsigned short* F   = (unsigned short*)((char*)d_ws + 8192);  // 4 KiB
    unsigned short* w1b = (unsigned short*)((char*)d_ws + 16384); // 16 MiB (bf16)

    build_tables<<<64, 64, 0, stream>>>(At, F);
    k_hw<<<2048, 256, 0, stream>>>(x, F, w1b);
    k_d<<<512, 256, 0, stream>>>(w1b, At, out);
}

// Round 11
// 52.169 us; speedup vs baseline: 1.0182x; 1.0182x over previous
//
#include <hip/hip_runtime.h>
#include <hip/hip_bf16.h>
#include <math.h>
#include <stdint.h>

// SpectralPooling: x (4,32,64,64,64) f32 -> out (4,32,32,32,32) f32.
// Separable: out[bc,k,j,l] = sum_{d,h,w} A[k,d]A[j,h]A[l,w] x[bc,d,h,w],
// A = (32x64) fused DCT64->crop32->IDCT32 matrix.
// k_hw (MFMA bf16, R9-exact): per slab (bc,d): U = X·A^T ; O^T = Ut·A^T -> w1b bf16
// k_d  (R11): 1024 blocks (bc x 2kh x 4q, 1 p/thread — the only geometry that
//       ever measured fast) + ALL 64 d-loads preloaded into registers in two
//       32-deep batches -> one latency exposure instead of eight.
//
// MFMA conventions (mfma_f32_16x16x32_bf16), HW-verified by R3-R10 passing:
//   A-op: lane m = lane&15, k = 8*(lane>>4)+jj ; B-op same map (k-perm cancels)
//   C/D : col = lane&15, row = 4*(lane>>4)+reg

#define PI_F 3.14159265358979323846f

typedef __attribute__((ext_vector_type(4))) float f32x4;
typedef __attribute__((ext_vector_type(8))) short bf16x8;

union U16x8 { uint4 q; bf16x8 v; uint32_t w[4]; };

// pair f32 -> packed bf16 (RNE) ; compiles to v_cvt_pk_bf16_f32
__device__ __forceinline__ uint32_t pk(float a, float b) {
    union { __hip_bfloat162 h; uint32_t u; } c;
    c.h = __float22bfloat162_rn(make_float2(a, b));
    return c.u;
}

__device__ __forceinline__ unsigned short bf16r(float x) {
    union { float f; uint32_t u; } c; c.f = x;
    uint32_t r = (c.u + 0x7FFFu + ((c.u >> 16) & 1u)) >> 16;  // RNE (table build only)
    return (unsigned short)r;
}

__device__ __forceinline__ float Aelem(int i, int d) {
    const float s1 = sqrtf(1.0f / 32.0f), s2 = sqrtf(2.0f / 32.0f);
    const float t1 = sqrtf(1.0f / 64.0f), t2 = sqrtf(2.0f / 64.0f);
    float acc = 0.f;
    for (int k = 0; k < 32; ++k) {
        int n1 = ((2 * i + 1) * k) & 127;   // cos(pi*n1/64)
        int n2 = ((2 * d + 1) * k) & 255;   // cos(pi*n2/128)
        float c1 = cosf((float)n1 * (PI_F / 64.0f));
        float c2 = cosf((float)n2 * (PI_F / 128.0f));
        acc += ((k == 0) ? s1 : s2) * ((k == 0) ? t1 : t2) * c1 * c2;
    }
    return acc;
}

// ---- tables: At[64][32] f32 (k_d) + F frag table bf16 (k_hw). 64 x 64. ----
__global__ __launch_bounds__(64) void build_tables(float* __restrict__ At,
                                                   unsigned short* __restrict__ F) {
    int e = blockIdx.x * 64 + threadIdx.x;
    if (e < 2048) {
        int d = e >> 5, i = e & 31;
        At[e] = Aelem(i, d);
    } else if (e < 4096) {
        int f = e - 2048;
        int jj = f & 7, lane = (f >> 3) & 63, tk = f >> 9;
        int tt = tk >> 1, kt = tk & 1;
        int row = tt * 16 + (lane & 15);
        int col = kt * 32 + ((lane >> 4) << 3) + jj;
        F[f] = bf16r(Aelem(row, col));
    }
}

// ---- k_hw: R9-exact. 4 waves/block, one slab per wave, wave-private LDS. ----
__global__ __launch_bounds__(256, 4) void k_hw(const float* __restrict__ x,
                                               const unsigned short* __restrict__ F,
                                               unsigned short* __restrict__ w1b) {
    __shared__ unsigned short Ut[4][2048];   // per-wave Ut[l][h] bf16, XOR-swizzled

    const int t = threadIdx.x;
    const int wv = t >> 6, ln = t & 63;
    const int lm = ln & 15, lg = ln >> 4;
    const size_t slab = (size_t)blockIdx.x * 4 + wv;

    // constant B-operand frags
    bf16x8 Ff[2][2];
    {
        const uint4* fp = (const uint4*)F;
        #pragma unroll
        for (int tt = 0; tt < 2; ++tt)
            #pragma unroll
            for (int kt = 0; kt < 2; ++kt) {
                U16x8 u; u.q = fp[(tt * 2 + kt) * 64 + ln];
                Ff[tt][kt] = u.v;
            }
    }

    // ---- issue all 16 x-loads up front ----
    const float* xs = x + slab * 4096;
    uint4 raw[16];
    #pragma unroll
    for (int mt = 0; mt < 4; ++mt)
        #pragma unroll
        for (int kt = 0; kt < 2; ++kt) {
            const uint4* p = (const uint4*)(xs + (mt * 16 + lm) * 64 + kt * 32 + (lg << 3));
            raw[(mt * 2 + kt) * 2 + 0] = p[0];
            raw[(mt * 2 + kt) * 2 + 1] = p[1];
        }

    // ---- stage B: U[h][l] = sum_w X[h][w] * A[l][w] ----
    f32x4 accu[4][2];
    #pragma unroll
    for (int mt = 0; mt < 4; ++mt)
        #pragma unroll
        for (int nt = 0; nt < 2; ++nt)
            accu[mt][nt] = (f32x4){0.f, 0.f, 0.f, 0.f};

    #pragma unroll
    for (int mt = 0; mt < 4; ++mt) {
        #pragma unroll
        for (int kt = 0; kt < 2; ++kt) {
            const float* f0 = (const float*)&raw[(mt * 2 + kt) * 2];
            U16x8 xf;
            #pragma unroll
            for (int e = 0; e < 4; ++e)
                xf.w[e] = pk(f0[2 * e], f0[2 * e + 1]);   // v_cvt_pk_bf16_f32
            #pragma unroll
            for (int nt = 0; nt < 2; ++nt)
                accu[mt][nt] = __builtin_amdgcn_mfma_f32_16x16x32_bf16(
                    xf.v, Ff[nt][kt], accu[mt][nt], 0, 0, 0);
        }
    }

    // ---- transpose U -> Ut[l][h] (bf16, XOR-swizzled), wave-private ----
    unsigned short* ut = Ut[wv];
    #pragma unroll
    for (int mt = 0; mt < 4; ++mt)
        #pragma unroll
        for (int nt = 0; nt < 2; ++nt) {
            int lo = nt * 16 + lm;               // Ut row (= l)
            int h0 = mt * 16 + (lg << 2);        // 4 consecutive h
            uint32_t w0 = pk(accu[mt][nt][0], accu[mt][nt][1]);
            uint32_t w1v = pk(accu[mt][nt][2], accu[mt][nt][3]);
            uint32_t byte = (uint32_t)(lo * 128 + 2 * h0);
            byte ^= (uint32_t)((lo & 7) << 4);   // bank swizzle
            *(uint2*)((char*)ut + byte) = make_uint2(w0, w1v);
        }
    __builtin_amdgcn_wave_barrier();

    // ---- stage C: O^T[l][j] = sum_h Ut[l][h] * A[j][h] ----
    f32x4 acco[2][2];
    #pragma unroll
    for (int mt = 0; mt < 2; ++mt)
        #pragma unroll
        for (int nt = 0; nt < 2; ++nt)
            acco[mt][nt] = (f32x4){0.f, 0.f, 0.f, 0.f};

    #pragma unroll
    for (int mt = 0; mt < 2; ++mt) {
        #pragma unroll
        for (int kt = 0; kt < 2; ++kt) {
            int lo = mt * 16 + lm;
            uint32_t byte = (uint32_t)(lo * 128 + kt * 64 + (lg << 4));
            byte ^= (uint32_t)((lo & 7) << 4);
            bf16x8 uf = *(const bf16x8*)((const char*)ut + byte);  // ds_read_b128
            #pragma unroll
            for (int nt = 0; nt < 2; ++nt)
                acco[mt][nt] = __builtin_amdgcn_mfma_f32_16x16x32_bf16(
                    uf, Ff[nt][kt], acco[mt][nt], 0, 0, 0);
        }
    }

    // ---- direct packed store: lane owns 4 consecutive l per (mt,nt) ----
    #pragma unroll
    for (int mt = 0; mt < 2; ++mt)
        #pragma unroll
        for (int nt = 0; nt < 2; ++nt) {
            uint32_t u0 = pk(acco[mt][nt][0], acco[mt][nt][1]);
            uint32_t u1 = pk(acco[mt][nt][2], acco[mt][nt][3]);
            int j  = nt * 16 + lm;
            int l0 = mt * 16 + (lg << 2);
            *(uint2*)(w1b + slab * 1024 + j * 32 + l0) = make_uint2(u0, u1);
        }
}

// ---- k_d: 1024 blocks (bc x 2 kh x 4 q), 1 p/thread, 64-deep reg preload ----
// out[bc][kh*16+kk][p] = sum_d At[d][kh*16+kk] * w1b[bc][d][p]
__global__ __launch_bounds__(256, 4) void k_d(const unsigned short* __restrict__ w1b,
                                              const float* __restrict__ At,
                                              float* __restrict__ out) {
    const int t = threadIdx.x;
    const int bc = blockIdx.x >> 3;
    const int kh = (blockIdx.x >> 2) & 1;
    const int q  = blockIdx.x & 3;
    const int p  = q * 256 + t;
    const unsigned short* src = w1b + (size_t)bc * 65536 + p;

    // preload ALL 64 strided loads into registers (2 x 32-deep batches;
    // fully unrolled + compile-time indices -> stays in VGPRs, ~95 total)
    uint32_t v[64];
    #pragma unroll
    for (int d = 0; d < 32; ++d) v[d] = (uint32_t)src[d * 1024];
    #pragma unroll
    for (int d = 32; d < 64; ++d) v[d] = (uint32_t)src[d * 1024];

    float acc[16];
    #pragma unroll
    for (int k = 0; k < 16; ++k) acc[k] = 0.f;

    #pragma unroll
    for (int d = 0; d < 64; ++d) {
        float xv = __uint_as_float(v[d] << 16);     // bf16 -> f32
        const float* arow = At + d * 32 + kh * 16;  // wave-uniform -> s_load
        #pragma unroll
        for (int k = 0; k < 16; ++k) acc[k] += arow[k] * xv;
    }

    float* dst = out + (size_t)bc * 32768 + (size_t)kh * 16384 + p;
    #pragma unroll
    for (int k = 0; k < 16; ++k) dst[k * 1024] = acc[k];
}

extern "C" void kernel_launch(void* const* d_in, const int* in_sizes, int n_in,
                              void* d_out, int out_size, void* d_ws, size_t ws_size,
                              hipStream_t stream) {
    const float* x = (const float*)d_in[0];
    float* out = (float*)d_out;

    float* At           = (float*)d_ws;                           // 8 KiB
    unsigned short* F   = (unsigned short*)((char*)d_ws + 8192);  // 4 KiB
    unsigned short* w1b = (unsigned short*)((char*)d_ws + 16384); // 16 MiB (bf16)

    build_tables<<<64, 64, 0, stream>>>(At, F);
    k_hw<<<2048, 256, 0, stream>>>(x, F, w1b);
    k_d<<<1024, 256, 0, stream>>>(w1b, At, out);
}

// Round 12
// 45.750 us; speedup vs baseline: 1.1610x; 1.1403x over previous
//
#include <hip/hip_runtime.h>
#include <hip/hip_bf16.h>
#include <math.h>
#include <stdint.h>

// SpectralPooling: x (4,32,64,64,64) f32 -> out (4,32,32,32,32) f32.
// Separable: out[bc,k,j,l] = sum_{d,h,w} A[k,d]A[j,h]A[l,w] x[bc,d,h,w],
// A = (32x64) fused DCT64->crop32->IDCT32 matrix.
// R12 = R9-exact restore (best measured: 45.9 us).
//   k_hw (MFMA bf16): per slab (bc,d): U = X·A^T ; O^T = Ut·A^T -> w1b bf16,
//        16 loads issued up front, cvt_pk conversions, direct packed store.
//   k_d: R4-exact geometry (1024 blocks, 1 p/thread, unroll-8) — measured
//        optimum vs 4 alternatives (512-blk, pk_fma, 4-way ks, 64-preload).
//
// MFMA conventions (mfma_f32_16x16x32_bf16), HW-verified by R3-R11 passing:
//   A-op: lane m = lane&15, k = 8*(lane>>4)+jj ; B-op same map (k-perm cancels)
//   C/D : col = lane&15, row = 4*(lane>>4)+reg

#define PI_F 3.14159265358979323846f

typedef __attribute__((ext_vector_type(4))) float f32x4;
typedef __attribute__((ext_vector_type(8))) short bf16x8;

union U16x8 { uint4 q; bf16x8 v; uint32_t w[4]; };

// pair f32 -> packed bf16 (RNE) ; compiles to v_cvt_pk_bf16_f32
__device__ __forceinline__ uint32_t pk(float a, float b) {
    union { __hip_bfloat162 h; uint32_t u; } c;
    c.h = __float22bfloat162_rn(make_float2(a, b));
    return c.u;
}

__device__ __forceinline__ unsigned short bf16r(float x) {
    union { float f; uint32_t u; } c; c.f = x;
    uint32_t r = (c.u + 0x7FFFu + ((c.u >> 16) & 1u)) >> 16;  // RNE (table build only)
    return (unsigned short)r;
}

__device__ __forceinline__ float Aelem(int i, int d) {
    const float s1 = sqrtf(1.0f / 32.0f), s2 = sqrtf(2.0f / 32.0f);
    const float t1 = sqrtf(1.0f / 64.0f), t2 = sqrtf(2.0f / 64.0f);
    float acc = 0.f;
    for (int k = 0; k < 32; ++k) {
        int n1 = ((2 * i + 1) * k) & 127;   // cos(pi*n1/64)
        int n2 = ((2 * d + 1) * k) & 255;   // cos(pi*n2/128)
        float c1 = cosf((float)n1 * (PI_F / 64.0f));
        float c2 = cosf((float)n2 * (PI_F / 128.0f));
        acc += ((k == 0) ? s1 : s2) * ((k == 0) ? t1 : t2) * c1 * c2;
    }
    return acc;
}

// ---- tables: At[64][32] f32 (k_d) + F frag table bf16 (k_hw). 16 blocks. ----
__global__ __launch_bounds__(256) void build_tables(float* __restrict__ At,
                                                    unsigned short* __restrict__ F) {
    int e = blockIdx.x * 256 + threadIdx.x;
    if (e < 2048) {
        int d = e >> 5, i = e & 31;
        At[e] = Aelem(i, d);
    } else if (e < 4096) {
        int f = e - 2048;
        int jj = f & 7, lane = (f >> 3) & 63, tk = f >> 9;
        int tt = tk >> 1, kt = tk & 1;
        int row = tt * 16 + (lane & 15);
        int col = kt * 32 + ((lane >> 4) << 3) + jj;
        F[f] = bf16r(Aelem(row, col));
    }
}

// ---- k_hw: 4 waves/block, one slab per wave, wave-private LDS only.
// launch_bounds(256,4): cap 128 VGPR -> 4 waves/SIMD (16 waves/CU).
__global__ __launch_bounds__(256, 4) void k_hw(const float* __restrict__ x,
                                               const unsigned short* __restrict__ F,
                                               unsigned short* __restrict__ w1b) {
    __shared__ unsigned short Ut[4][2048];   // per-wave Ut[l][h] bf16, XOR-swizzled

    const int t = threadIdx.x;
    const int wv = t >> 6, ln = t & 63;
    const int lm = ln & 15, lg = ln >> 4;
    const size_t slab = (size_t)blockIdx.x * 4 + wv;

    // constant B-operand frags
    bf16x8 Ff[2][2];
    {
        const uint4* fp = (const uint4*)F;
        #pragma unroll
        for (int tt = 0; tt < 2; ++tt)
            #pragma unroll
            for (int kt = 0; kt < 2; ++kt) {
                U16x8 u; u.q = fp[(tt * 2 + kt) * 64 + ln];
                Ff[tt][kt] = u.v;
            }
    }

    // ---- issue all 16 x-loads up front ----
    const float* xs = x + slab * 4096;
    uint4 raw[16];
    #pragma unroll
    for (int mt = 0; mt < 4; ++mt)
        #pragma unroll
        for (int kt = 0; kt < 2; ++kt) {
            const uint4* p = (const uint4*)(xs + (mt * 16 + lm) * 64 + kt * 32 + (lg << 3));
            raw[(mt * 2 + kt) * 2 + 0] = p[0];
            raw[(mt * 2 + kt) * 2 + 1] = p[1];
        }

    // ---- stage B: U[h][l] = sum_w X[h][w] * A[l][w] ----
    f32x4 accu[4][2];
    #pragma unroll
    for (int mt = 0; mt < 4; ++mt)
        #pragma unroll
        for (int nt = 0; nt < 2; ++nt)
            accu[mt][nt] = (f32x4){0.f, 0.f, 0.f, 0.f};

    #pragma unroll
    for (int mt = 0; mt < 4; ++mt) {
        #pragma unroll
        for (int kt = 0; kt < 2; ++kt) {
            const float* f0 = (const float*)&raw[(mt * 2 + kt) * 2];
            U16x8 xf;
            #pragma unroll
            for (int e = 0; e < 4; ++e)
                xf.w[e] = pk(f0[2 * e], f0[2 * e + 1]);   // v_cvt_pk_bf16_f32
            #pragma unroll
            for (int nt = 0; nt < 2; ++nt)
                accu[mt][nt] = __builtin_amdgcn_mfma_f32_16x16x32_bf16(
                    xf.v, Ff[nt][kt], accu[mt][nt], 0, 0, 0);
        }
    }

    // ---- transpose U -> Ut[l][h] (bf16, XOR-swizzled), wave-private ----
    unsigned short* ut = Ut[wv];
    #pragma unroll
    for (int mt = 0; mt < 4; ++mt)
        #pragma unroll
        for (int nt = 0; nt < 2; ++nt) {
            int lo = nt * 16 + lm;               // Ut row (= l)
            int h0 = mt * 16 + (lg << 2);        // 4 consecutive h
            uint32_t w0 = pk(accu[mt][nt][0], accu[mt][nt][1]);
            uint32_t w1v = pk(accu[mt][nt][2], accu[mt][nt][3]);
            uint32_t byte = (uint32_t)(lo * 128 + 2 * h0);
            byte ^= (uint32_t)((lo & 7) << 4);   // bank swizzle
            *(uint2*)((char*)ut + byte) = make_uint2(w0, w1v);
        }
    __builtin_amdgcn_wave_barrier();

    // ---- stage C: O^T[l][j] = sum_h Ut[l][h] * A[j][h] ----
    f32x4 acco[2][2];
    #pragma unroll
    for (int mt = 0; mt < 2; ++mt)
        #pragma unroll
        for (int nt = 0; nt < 2; ++nt)
            acco[mt][nt] = (f32x4){0.f, 0.f, 0.f, 0.f};

    #pragma unroll
    for (int mt = 0; mt < 2; ++mt) {
        #pragma unroll
        for (int kt = 0; kt < 2; ++kt) {
            int lo = mt * 16 + lm;
            uint32_t byte = (uint32_t)(lo * 128 + kt * 64 + (lg << 4));
            byte ^= (uint32_t)((lo & 7) << 4);
            bf16x8 uf = *(const bf16x8*)((const char*)ut + byte);  // ds_read_b128
            #pragma unroll
            for (int nt = 0; nt < 2; ++nt)
                acco[mt][nt] = __builtin_amdgcn_mfma_f32_16x16x32_bf16(
                    uf, Ff[nt][kt], acco[mt][nt], 0, 0, 0);
        }
    }

    // ---- direct packed store: lane owns 4 consecutive l per (mt,nt) ----
    #pragma unroll
    for (int mt = 0; mt < 2; ++mt)
        #pragma unroll
        for (int nt = 0; nt < 2; ++nt) {
            uint32_t u0 = pk(acco[mt][nt][0], acco[mt][nt][1]);
            uint32_t u1 = pk(acco[mt][nt][2], acco[mt][nt][3]);
            int j  = nt * 16 + lm;
            int l0 = mt * 16 + (lg << 2);
            *(uint2*)(w1b + slab * 1024 + j * 32 + l0) = make_uint2(u0, u1);
        }
}

// ---- k_d: R4-exact (measured-best). grid = 128 bc x 2 kh x 4 q = 1024 ----
// out[bc][kh*16+kk][p] = sum_d At[d][kh*16+kk] * w1b[bc][d][p]
__global__ __launch_bounds__(256) void k_d(const unsigned short* __restrict__ w1b,
                                           const float* __restrict__ At,
                                           float* __restrict__ out) {
    const int t = threadIdx.x;
    const int bc = blockIdx.x >> 3;
    const int kh = (blockIdx.x >> 2) & 1;
    const int q  = blockIdx.x & 3;
    const int p  = q * 256 + t;
    const unsigned short* src = w1b + (size_t)bc * 65536 + p;
    float acc[16];
    #pragma unroll
    for (int k = 0; k < 16; ++k) acc[k] = 0.f;
    #pragma unroll 8
    for (int d = 0; d < 64; ++d) {
        uint32_t u = (uint32_t)src[d * 1024];
        float v = __uint_as_float(u << 16);       // bf16 -> f32
        const float* arow = At + d * 32 + kh * 16;  // wave-uniform -> s_load
        #pragma unroll
        for (int k = 0; k < 16; ++k) acc[k] += arow[k] * v;
    }
    float* dst = out + (size_t)bc * 32768 + (size_t)kh * 16384 + p;
    #pragma unroll
    for (int k = 0; k < 16; ++k) dst[k * 1024] = acc[k];
}

extern "C" void kernel_launch(void* const* d_in, const int* in_sizes, int n_in,
                              void* d_out, int out_size, void* d_ws, size_t ws_size,
                              hipStream_t stream) {
    const float* x = (const float*)d_in[0];
    float* out = (float*)d_out;

    float* At           = (float*)d_ws;                           // 8 KiB
    unsigned short* F   = (unsigned short*)((char*)d_ws + 8192);  // 4 KiB
    unsigned short* w1b = (unsigned short*)((char*)d_ws + 16384); // 16 MiB (bf16)

    build_tables<<<16, 256, 0, stream>>>(At, F);
    k_hw<<<2048, 256, 0, stream>>>(x, F, w1b);
    k_d<<<1024, 256, 0, stream>>>(w1b, At, out);
}